// Round 5
// baseline (366.301 us; speedup 1.0000x reference)
//
#include <hip/hip_runtime.h>
#include <hip/hip_bf16.h>

// Problem constants (B=8192, IN=H=1024)
#define BATCH 8192
#define HDIM  1024
#define KDIM  2048   // IN + H concatenated
#define NDIM  4096   // 4*H

__device__ inline unsigned short f2bf(float x) {
    unsigned int u = __float_as_uint(x);
    unsigned int r = (u + 0x7fffu + ((u >> 16) & 1u)) >> 16;
    return (unsigned short)r;
}
__device__ inline float bf2f(unsigned short u) {
    return __uint_as_float((unsigned int)u << 16);
}

// Merged converter:
//  Wb [4096,2048] bf16: row n = [w_i[n] | w_h[n]], w_i half zeroed for rows
//  2048..3071 (chunk i_gc of gi is unused by the reference).
//  Xb [8192,2048] bf16: row r = [input[r] | h_prev[r]]
__global__ __launch_bounds__(256) void convert_kernel(
    const float* __restrict__ wi, const float* __restrict__ wh,
    const float* __restrict__ input, const float* __restrict__ h_prev,
    unsigned short* __restrict__ Wb, unsigned short* __restrict__ Xb)
{
    int idx = blockIdx.x * 256 + threadIdx.x;
    const int NW = NDIM * 512;              // weight-element groups
    float4 v;
    unsigned short* dst;
    if (idx < NW) {
        int n = idx >> 9;
        int k = (idx & 511) << 2;
        if (k < 1024) {
            if (n >= 2048 && n < 3072) v = make_float4(0.f, 0.f, 0.f, 0.f);
            else                       v = *(const float4*)(wi + (size_t)n * 1024 + k);
        } else {
            v = *(const float4*)(wh + (size_t)n * 1024 + (k - 1024));
        }
        dst = Wb + (size_t)n * KDIM + k;
    } else {
        int j = idx - NW;
        int r = j >> 9;
        int k = (j & 511) << 2;
        if (k < 1024) v = *(const float4*)(input  + (size_t)r * 1024 + k);
        else          v = *(const float4*)(h_prev + (size_t)r * 1024 + (k - 1024));
        dst = Xb + (size_t)r * KDIM + k;
    }
    ushort4 o;
    o.x = f2bf(v.x); o.y = f2bf(v.y); o.z = f2bf(v.z); o.w = f2bf(v.w);
    *(ushort4*)dst = o;
}

// ---------------------------------------------------------------------------
// GEMM: G[M,N](bf16) = A[M,K](bf16) * Bw[N,K](bf16)^T
// 256x128 tile, 512 threads (8 waves, 4m x 2n of 64x64 wave-tiles), BK=64.
// R5: 32x32x16 MFMA (4000 vs 3378 FLOP/cyc/CU, half the instructions) and
// stripe-major block order (4 n-stripes of 8 tiles; 4 MB B-stripe fits
// per-XCD L2 -> predicted fetch 211 -> ~155 MB).
// XOR-swizzled LDS k-chunks -> 0 bank conflicts (verified R2-R4).
// ---------------------------------------------------------------------------
#define BM 256
#define BN 128
#define BK 64    // bf16 elems per row; 128 B

typedef __attribute__((ext_vector_type(8))) short bf16x8;
typedef __attribute__((ext_vector_type(16))) float f32x16;

__global__ __launch_bounds__(512) void gemm_bt_kernel(
    const unsigned short* __restrict__ A,
    const unsigned short* __restrict__ Bw,
    unsigned short* __restrict__ G,
    int M)
{
    __shared__ unsigned short As[BM * BK];   // 32 KB
    __shared__ unsigned short Bs[BN * BK];   // 16 KB

    const int tid  = threadIdx.x;
    const int lane = tid & 63;
    const int wave = tid >> 6;               // 0..7

    // stripe-major order: 4 stripes of 8 n-tiles; within a stripe, m-fastest
    // groups of 8 consecutive n so dispatch-adjacent blocks share a 4 MB
    // B-stripe (fits per-XCD L2) while A is swept once per stripe.
    const int m_tiles = M / BM;
    const int per_stripe = m_tiles * 8;
    const int s   = blockIdx.x / per_stripe;
    const int rem = blockIdx.x % per_stripe;
    const int bm  = (rem >> 3) * BM;
    const int bn  = ((s << 3) + (rem & 7)) * BN;

    f32x16 acc[2][2] = {};

    const int wm = (wave >> 1) * 64;         // 0,64,128,192
    const int wn = (wave & 1) * 64;          // 0,64

    // staging: lane l covers row (l>>3) of its 8-row group, LDS chunk (l&7).
    // XOR swizzle: LDS row r, position p holds global 16B k-chunk p ^ (r&7).
    const int srow = lane >> 3;              // 0..7
    const int c_sw = (lane & 7) ^ srow;      // global 16B-chunk to fetch

    int k0 = 0;
    if (bn >= 2048 && bn < 3072) k0 = 1024;  // w_i half of these rows is zero

    for (; k0 < KDIM; k0 += BK) {
        // A: 4 loads/wave covering rows [wave*32, wave*32+32)
#pragma unroll
        for (int p = 0; p < 4; ++p) {
            const int rbase = wave * 32 + p * 8;
            const unsigned short* gA =
                A + (size_t)(bm + rbase + srow) * KDIM + k0 + c_sw * 8;
            __builtin_amdgcn_global_load_lds(
                (const __attribute__((address_space(1))) void*)gA,
                (__attribute__((address_space(3))) void*)&As[rbase * BK], 16, 0, 0);
        }
        // B: 2 loads/wave covering rows [wave*16, wave*16+16)
#pragma unroll
        for (int p = 0; p < 2; ++p) {
            const int rbase = wave * 16 + p * 8;
            const unsigned short* gB =
                Bw + (size_t)(bn + rbase + srow) * KDIM + k0 + c_sw * 8;
            __builtin_amdgcn_global_load_lds(
                (const __attribute__((address_space(1))) void*)gB,
                (__attribute__((address_space(3))) void*)&Bs[rbase * BK], 16, 0, 0);
        }
        __syncthreads();

        // 32x32x16 MFMA: A-frag row=lane&31, k=(lane>>5)*8+j.
        // Per BK=64: 4 k-steps of 16; 16B-chunk index = ks*2 + (lane>>5).
#pragma unroll
        for (int ks = 0; ks < 4; ++ks) {
            const int kc = ks * 2 + (lane >> 5);
            bf16x8 af[2], bfr[2];
#pragma unroll
            for (int mm = 0; mm < 2; ++mm) {
                const int ra = wm + mm * 32 + (lane & 31);
                af[mm]  = *(const bf16x8*)&As[ra * BK + ((kc ^ (ra & 7)) * 8)];
                const int rb = wn + mm * 32 + (lane & 31);
                bfr[mm] = *(const bf16x8*)&Bs[rb * BK + ((kc ^ (rb & 7)) * 8)];
            }
#pragma unroll
            for (int mm = 0; mm < 2; ++mm)
#pragma unroll
                for (int nn = 0; nn < 2; ++nn)
                    acc[mm][nn] = __builtin_amdgcn_mfma_f32_32x32x16_bf16(
                        af[mm], bfr[nn], acc[mm][nn], 0, 0, 0);
        }
        __syncthreads();
    }

    // Epilogue: 32x32 C/D mapping col=lane&31,
    // row=(reg&3)+8*(reg>>2)+4*(lane>>5) (m74/m101-verified). bf16 stores.
#pragma unroll
    for (int mm = 0; mm < 2; ++mm) {
#pragma unroll
        for (int nn = 0; nn < 2; ++nn) {
#pragma unroll
            for (int r = 0; r < 16; ++r) {
                int row = bm + wm + mm * 32 + (r & 3) + 8 * (r >> 2) + 4 * (lane >> 5);
                int col = bn + wn + nn * 32 + (lane & 31);
                G[(size_t)row * NDIM + col] = f2bf(acc[mm][nn][r]);
            }
        }
    }
}

// ---------------------------------------------------------------------------
// Elementwise: wave-per-row, pure shuffle reductions, no barriers / LDS.
// G (bf16) row layout: [s0=i_i+h_i | s1=i_f+h_f | s2=h_g | s3=i_o+h_o]
// Lane l covers cols {j*512 + l*8 + e : j in 0..1, e in 0..7}.
// ---------------------------------------------------------------------------
__device__ inline float sigmoid_f(float x) { return 1.f / (1.f + __expf(-x)); }
// safe fast tanh: exact +/-1 saturation at both ends
__device__ inline float tanh_f(float x) { return 1.f - 2.f / (__expf(2.f * x) + 1.f); }

typedef __attribute__((ext_vector_type(8))) unsigned short us8;

__device__ inline void wstats(const float* x, float& mu, float& rs)
{
    float s = 0.f, q = 0.f;
#pragma unroll
    for (int e = 0; e < 16; ++e) { s += x[e]; q += x[e] * x[e]; }
#pragma unroll
    for (int o = 1; o < 64; o <<= 1) {
        s += __shfl_xor(s, o);
        q += __shfl_xor(q, o);
    }
    mu = s * (1.f / 1024.f);
    float var = q * (1.f / 1024.f) - mu * mu;
    rs = rsqrtf(var + 1e-5f);
}

// 16 bf16 -> fp32 per thread: two 16B ushort8 loads
#define LOADG16(dst, basep)                                            \
    _Pragma("unroll")                                                  \
    for (int j = 0; j < 2; ++j) {                                      \
        us8 t = *(const us8*)((basep) + j * 512 + cbase);              \
        _Pragma("unroll")                                              \
        for (int e = 0; e < 8; ++e) dst[j * 8 + e] = bf2f(t[e]);       \
    }

// 16 fp32 per thread (params / c_prev): four float4 loads
#define LOADF16(dst, basep)                                            \
    _Pragma("unroll")                                                  \
    for (int j = 0; j < 2; ++j) {                                      \
        float4 a = *(const float4*)((basep) + j * 512 + cbase);        \
        float4 b = *(const float4*)((basep) + j * 512 + cbase + 4);    \
        dst[j * 8 + 0] = a.x; dst[j * 8 + 1] = a.y;                    \
        dst[j * 8 + 2] = a.z; dst[j * 8 + 3] = a.w;                    \
        dst[j * 8 + 4] = b.x; dst[j * 8 + 5] = b.y;                    \
        dst[j * 8 + 6] = b.z; dst[j * 8 + 7] = b.w;                    \
    }

__global__ __launch_bounds__(256) void lstm_ew_kernel(
    const unsigned short* __restrict__ G,
    const float* __restrict__ c_prev,
    const float* __restrict__ p0g, const float* __restrict__ p0b,
    const float* __restrict__ p1g, const float* __restrict__ p1b,
    const float* __restrict__ p2g, const float* __restrict__ p2b,
    const float* __restrict__ p3g, const float* __restrict__ p3b,
    const float* __restrict__ p4g, const float* __restrict__ p4b,
    float* __restrict__ out_h, float* __restrict__ out_c,
    int row_base)
{
    const int lane  = threadIdx.x & 63;
    const int wave  = threadIdx.x >> 6;
    const int r     = blockIdx.x * 4 + wave;
    const int grow  = row_base + r;
    const int cbase = lane * 8;

    const unsigned short* Grow = G + (size_t)r * NDIM;

    float tmp[16], pg[16], pb[16];
    float ig[16], cm[16], og[16];
    float mu, rs;

    // i gate: sigmoid(LN(i_i+h_i; ln_i))
    LOADG16(tmp, Grow);
    wstats(tmp, mu, rs);
    LOADF16(pg, p0g); LOADF16(pb, p0b);
#pragma unroll
    for (int e = 0; e < 16; ++e)
        ig[e] = sigmoid_f((tmp[e] - mu) * rs * pg[e] + pb[e]);

    // f gate: sigmoid(LN(i_f+h_f; ln_h)); cm = f * c_prev
    LOADG16(tmp, Grow + 1024);
    wstats(tmp, mu, rs);
    LOADF16(pg, p1g); LOADF16(pb, p1b);
    LOADF16(cm, c_prev + (size_t)grow * HDIM);
#pragma unroll
    for (int e = 0; e < 16; ++e)
        cm[e] *= sigmoid_f((tmp[e] - mu) * rs * pg[e] + pb[e]);

    // g gate: tanh(LN(i_g + h_g; ln_g))  <- faithful bug: i_g is sigmoided gate
    LOADG16(tmp, Grow + 2048);
#pragma unroll
    for (int e = 0; e < 16; ++e) tmp[e] += ig[e];
    wstats(tmp, mu, rs);
    LOADF16(pg, p2g); LOADF16(pb, p2b);
#pragma unroll
    for (int e = 0; e < 16; ++e)
        cm[e] += ig[e] * tanh_f((tmp[e] - mu) * rs * pg[e] + pb[e]);

    // o gate: sigmoid(LN(i_o+h_o; ln_o))
    LOADG16(tmp, Grow + 3072);
    wstats(tmp, mu, rs);
    LOADF16(pg, p3g); LOADF16(pb, p3b);
#pragma unroll
    for (int e = 0; e < 16; ++e)
        og[e] = sigmoid_f((tmp[e] - mu) * rs * pg[e] + pb[e]);

    // c_new = LN(cm; ln_c); h_new = o * tanh(c_new)
    wstats(cm, mu, rs);
    LOADF16(pg, p4g); LOADF16(pb, p4b);
    float cn[16], hn[16];
#pragma unroll
    for (int e = 0; e < 16; ++e) {
        cn[e] = (cm[e] - mu) * rs * pg[e] + pb[e];
        hn[e] = og[e] * tanh_f(cn[e]);
    }

    float* oh = out_h + (size_t)grow * HDIM;
    float* oc = out_c + (size_t)grow * HDIM;
#pragma unroll
    for (int j = 0; j < 2; ++j) {
        *(float4*)(oh + j * 512 + cbase) =
            make_float4(hn[j*8+0], hn[j*8+1], hn[j*8+2], hn[j*8+3]);
        *(float4*)(oh + j * 512 + cbase + 4) =
            make_float4(hn[j*8+4], hn[j*8+5], hn[j*8+6], hn[j*8+7]);
        *(float4*)(oc + j * 512 + cbase) =
            make_float4(cn[j*8+0], cn[j*8+1], cn[j*8+2], cn[j*8+3]);
        *(float4*)(oc + j * 512 + cbase + 4) =
            make_float4(cn[j*8+4], cn[j*8+5], cn[j*8+6], cn[j*8+7]);
    }
}

extern "C" void kernel_launch(void* const* d_in, const int* in_sizes, int n_in,
                              void* d_out, int out_size, void* d_ws, size_t ws_size,
                              hipStream_t stream)
{
    const float* input  = (const float*)d_in[0];
    const float* h_prev = (const float*)d_in[1];
    const float* c_prev = (const float*)d_in[2];
    const float* w_i    = (const float*)d_in[3];
    const float* w_h    = (const float*)d_in[4];
    const float* lng[10];
    for (int i = 0; i < 10; ++i) lng[i] = (const float*)d_in[5 + i];

    // Workspace: Xb bf16 [8192,2048] | Wb bf16 [4096,2048] | G bf16 [chunk,4096]
    unsigned short* Xb = (unsigned short*)d_ws;
    size_t xb_bytes = (size_t)BATCH * KDIM * 2;
    unsigned short* Wb = (unsigned short*)((char*)d_ws + xb_bytes);
    size_t wb_bytes = (size_t)NDIM * KDIM * 2;
    unsigned short* G = (unsigned short*)((char*)d_ws + xb_bytes + wb_bytes);

    size_t g_avail = (ws_size > xb_bytes + wb_bytes) ? (ws_size - xb_bytes - wb_bytes) : 0;
    long max_rows = (long)(g_avail / ((size_t)NDIM * sizeof(unsigned short)));
    int chunk = (max_rows >= BATCH) ? BATCH : (int)((max_rows / BM) * BM);
    if (chunk <= 0) chunk = BM;   // last-resort assumption

    convert_kernel<<<(NDIM * 512 + BATCH * 512) / 256, 256, 0, stream>>>(
        w_i, w_h, input, h_prev, Wb, Xb);

    float* out_h = (float*)d_out;
    float* out_c = out_h + (size_t)BATCH * HDIM;

    for (int rb = 0; rb < BATCH; rb += chunk) {
        int rows = (BATCH - rb < chunk) ? (BATCH - rb) : chunk;
        gemm_bt_kernel<<<(rows / BM) * (NDIM / BN), 512, 0, stream>>>(
            Xb + (size_t)rb * KDIM, Wb, G, rows);
        lstm_ew_kernel<<<rows / 4, 256, 0, stream>>>(
            G, c_prev, lng[0], lng[1], lng[2], lng[3], lng[4],
            lng[5], lng[6], lng[7], lng[8], lng[9], out_h, out_c, rb);
    }
}